// Round 5
// baseline (1933.876 us; speedup 1.0000x reference)
//
#include <hip/hip_runtime.h>
#include <math.h>

#define TPI  4096
#define TT   32768
#define DIN  1176
#define KP   1184
#define DM   1024
#define NE   8
#define BN   64
#define NL   4
#define DOUT 4096
#define BINCAP 32768

typedef __attribute__((ext_vector_type(4))) float floatx4;
typedef __attribute__((ext_vector_type(8))) short bf16x8;
typedef unsigned int uint;

__device__ inline short f2bf(float x) {
    unsigned u = __float_as_uint(x);
    u += 0x7fffu + ((u >> 16) & 1u);
    return (short)(u >> 16);
}
__device__ inline float bf2f(short h) {
    return __uint_as_float(((unsigned)(unsigned short)h) << 16);
}

#define GLP(p) ((const __attribute__((address_space(1))) void*)(p))
#define LDSP(p) ((__attribute__((address_space(3))) void*)(p))
#define ASYNC16(g, s) __builtin_amdgcn_global_load_lds(GLP(g), LDSP(s), 16, 0, 0)

// ws layout (bytes)
#define OFF_H0    0ul
#define OFF_H1    67108864ul
#define OFF_XB    134217728ul      // 77,594,624 B
#define OFF_WBT   211812352ul      // 2,424,832
#define OFF_E1T   214237184ul      // 4,194,304
#define OFF_E2T   218431488ul      // 4,194,304
#define OFF_BTOK  222625792ul      // 64*32768*4 = 8,388,608
#define OFF_BW1   231014400ul      // 8,388,608
#define OFF_BW2   239403008ul      // 8,388,608
#define OFF_WQ    247791616ul      // 16,384
#define OFF_Z     247808000ul
// Z: 0 counts[256]i | 1024 nwork[16]i | 1088 sum_probs[256]f | 2112 mask_cnt[256]f
//    3136 g[8192]f | 35904 hsg[512]f
#define Z_BYTES   37952ul
#define OFF_RB    247845952ul      // 1024
#define OFF_WRT   247846976ul      // 131072

// ---------- convert X (f32) -> Xb (bf16, KP-padded)
__global__ __launch_bounds__(256) void convx_kernel(
    const float* __restrict__ X, short* __restrict__ Xb)
{
    const long row = blockIdx.x;
    const float* src = X + row * (long)DIN;
    short* dst = Xb + row * (long)KP;
    for (int i = threadIdx.x; i < 296; i += 256) {
        short4 s;
        if (i < 294) {
            float4 v = *(const float4*)(src + i * 4);
            s.x = f2bf(v.x); s.y = f2bf(v.y); s.z = f2bf(v.z); s.w = f2bf(v.w);
        } else {
            s.x = 0; s.y = 0; s.z = 0; s.w = 0;
        }
        *(short4*)(dst + i * 4) = s;
    }
}

// ---------- generic transpose: dst[n][k] (row len DK) = src[k][n]
__global__ __launch_bounds__(256) void transp_kernel(
    const float* __restrict__ src, short* __restrict__ dst, int RS, int CS, int DK)
{
    __shared__ float tb[64][65];
    const int kt = blockIdx.x * 64, nt = blockIdx.y * 64;
    const long sb = (long)blockIdx.z * RS * CS;
    const long db = (long)blockIdx.z * CS * DK;
    const int rr = threadIdx.x >> 6, cc = threadIdx.x & 63;
#pragma unroll
    for (int i = 0; i < 16; ++i) {
        int r = i * 4 + rr;
        int k = kt + r, n = nt + cc;
        tb[r][cc] = (k < RS && n < CS) ? src[sb + (long)k * CS + n] : 0.0f;
    }
    __syncthreads();
#pragma unroll
    for (int i = 0; i < 16; ++i) {
        int r = i * 4 + rr;
        int n = nt + r, k = kt + cc;
        if (n < CS && k < DK) dst[db + (long)n * DK + k] = f2bf(tb[cc][r]);
    }
}

// ---------- router weights: wrT[l][16][1024], e>=8 zero
__global__ __launch_bounds__(256) void wrt_kernel(
    const float* __restrict__ w_rimg, short* __restrict__ wrT)
{
    const int l = blockIdx.x >> 4, e = blockIdx.x & 15;
    short* dst = wrT + ((long)l * 16 + e) * 1024;
    if (e < 8) {
        const float* src = w_rimg + (long)l * 8192 + e;
        for (int k = threadIdx.x; k < 1024; k += 256) dst[k] = f2bf(src[k * 8]);
    } else {
        for (int k = threadIdx.x; k < 1024; k += 256) dst[k] = 0;
    }
}

// ---------- in_proj MFMA GEMM
__global__ __launch_bounds__(256) void gemm_in_mfma(
    const short* __restrict__ Xb, const short* __restrict__ Wbt, short* __restrict__ Hb)
{
    __shared__ __align__(16) short As[128 * 32];
    __shared__ __align__(16) short Bs[128 * 32];
    const int tid = threadIdx.x;
    const int m0 = blockIdx.x * 128, n0 = blockIdx.y * 128;
    const int w = tid >> 6, lane = tid & 63;
    const int quad = lane >> 4, l15 = lane & 15;
    const int wm = (w >> 1) * 64, wn = (w & 1) * 64;

    floatx4 acc[4][4];
#pragma unroll
    for (int i = 0; i < 4; ++i)
#pragma unroll
        for (int j = 0; j < 4; ++j) acc[i][j] = 0.0f;

    const int r0 = tid >> 2, kof = (tid & 3) * 8;
    const int r1 = (tid + 256) >> 2;
    const short* a0p = Xb + (long)(m0 + r0) * KP + kof;
    const short* a1p = Xb + (long)(m0 + r1) * KP + kof;
    const short* b0p = Wbt + (long)(n0 + r0) * KP + kof;
    const short* b1p = Wbt + (long)(n0 + r1) * KP + kof;
    short* as0 = As + tid * 8;
    short* as1 = As + (tid + 256) * 8;
    short* bs0 = Bs + tid * 8;
    short* bs1 = Bs + (tid + 256) * 8;

    for (int k0 = 0; k0 < KP; k0 += 32) {
        __syncthreads();
        ASYNC16(a0p + k0, as0);
        ASYNC16(a1p + k0, as1);
        ASYNC16(b0p + k0, bs0);
        ASYNC16(b1p + k0, bs1);
        __syncthreads();
        bf16x8 af[4], bfr[4];
#pragma unroll
        for (int i = 0; i < 4; ++i)
            af[i] = *(const bf16x8*)&As[(wm + i * 16 + l15) * 32 + quad * 8];
#pragma unroll
        for (int j = 0; j < 4; ++j)
            bfr[j] = *(const bf16x8*)&Bs[(wn + j * 16 + l15) * 32 + quad * 8];
#pragma unroll
        for (int i = 0; i < 4; ++i)
#pragma unroll
            for (int j = 0; j < 4; ++j)
                acc[i][j] = __builtin_amdgcn_mfma_f32_16x16x32_bf16(af[i], bfr[j], acc[i][j], 0, 0, 0);
    }
#pragma unroll
    for (int i = 0; i < 4; ++i)
#pragma unroll
        for (int j = 0; j < 4; ++j)
#pragma unroll
            for (int r = 0; r < 4; ++r)
                Hb[(long)(m0 + wm + i * 16 + quad * 4 + r) * DM + n0 + wn + j * 16 + l15] =
                    f2bf(acc[i][j][r]);
}

// ---------- column mean
__global__ __launch_bounds__(256) void colmean_kernel(
    const short* __restrict__ Hb, float* __restrict__ outp)
{
    const int col = blockIdx.x * 256 + threadIdx.x;
    const int img = blockIdx.y;
    const int t0 = blockIdx.z * 256;
    const short* p = Hb + ((long)img * TPI + t0) * DM + col;
    float s = 0.0f;
#pragma unroll 8
    for (int t = 0; t < 256; ++t) s += bf2f(p[(long)t * DM]);
    atomicAdd(&outp[img * DM + col], s * (1.0f / 4096.0f));
}

// ---------- skin stage 1
__global__ __launch_bounds__(256) void skin1_kernel(
    const float* __restrict__ g, const float* __restrict__ w_sc1,
    const float* __restrict__ b_sc1, float* __restrict__ hsg)
{
    __shared__ float red[4][64];
    const int img = blockIdx.x;
    const int part = threadIdx.x >> 6, c = threadIdx.x & 63;
    float s = 0.0f;
    for (int i = 0; i < 256; ++i) {
        int d = part * 256 + i;
        s += g[img * DM + d] * w_sc1[d * 64 + c];
    }
    red[part][c] = s;
    __syncthreads();
    if (part == 0) {
        float v = red[0][c] + red[1][c] + red[2][c] + red[3][c] + b_sc1[c];
        hsg[img * 64 + c] = fmaxf(v, 0.0f);
    }
}

// ---------- skin stage 2
__global__ __launch_bounds__(256) void skin2_kernel(
    const float* __restrict__ hsg, const float* __restrict__ w_sc2, const float* __restrict__ b_sc2,
    const float* __restrict__ w_rskin, float* __restrict__ skin_logits_out, float* __restrict__ rb)
{
    __shared__ float l3[24];
    __shared__ float sp[24];
    const int tid = threadIdx.x;
    if (tid < 24) {
        int img = tid / 3, j = tid % 3;
        float s = b_sc2[j];
        for (int c = 0; c < 64; ++c) s += hsg[img * 64 + c] * w_sc2[c * 3 + j];
        l3[tid] = s;
        skin_logits_out[tid] = s;
    }
    __syncthreads();
    if (tid < 8) {
        float v0 = l3[tid * 3], v1 = l3[tid * 3 + 1], v2 = l3[tid * 3 + 2];
        float m = fmaxf(v0, fmaxf(v1, v2));
        float e0 = expf(v0 - m), e1 = expf(v1 - m), e2 = expf(v2 - m);
        float inv = 1.0f / (e0 + e1 + e2);
        sp[tid * 3] = e0 * inv; sp[tid * 3 + 1] = e1 * inv; sp[tid * 3 + 2] = e2 * inv;
    }
    __syncthreads();
    {
        int l = tid >> 6, img = (tid >> 3) & 7, e = tid & 7;
        float s = 0.0f;
#pragma unroll
        for (int c = 0; c < 3; ++c) s += sp[img * 3 + c] * w_rskin[(l * 3 + c) * 8 + e];
        rb[tid] = s;
    }
}

// ---------- wave-autonomous router: 16 tokens/wave, no LDS, no barriers.
// logits via MFMA (A = H rows direct-global, B = wrT direct-global), in-wave
// softmax/top2 via shfl_xor, direct binning into fixed-capacity pair bins.
__global__ __launch_bounds__(256) void router_kernel(
    const short* __restrict__ Hb, const short* __restrict__ wrT, const float* __restrict__ rb,
    int* __restrict__ counts, int* __restrict__ btok, float* __restrict__ bw1, float* __restrict__ bw2,
    float* __restrict__ sum_probs, float* __restrict__ mask_cnt, int l)
{
    const int tid = threadIdx.x;
    const int w = tid >> 6, lane = tid & 63;
    const int quad = lane >> 4, l15 = lane & 15;
    const int tok0w = blockIdx.x * 64 + w * 16;
    const int img = tok0w >> 12;

    const short* arow = Hb + (long)(tok0w + l15) * DM + quad * 8;
    const short* brow = wrT + ((long)l * 16 + l15) * 1024 + quad * 8;

    floatx4 acc = 0.0f;
#pragma unroll 8
    for (int k0 = 0; k0 < DM; k0 += 32) {
        bf16x8 a = *(const bf16x8*)(arow + k0);
        bf16x8 b = *(const bf16x8*)(brow + k0);
        acc = __builtin_amdgcn_mfma_f32_16x16x32_bf16(a, b, acc, 0, 0, 0);
    }

    const float rbv = rb[l * 64 + img * 8 + (l15 & 7)];
    float pr[4]; int i1r[4], i2r[4]; float w1r[4], w2r[4];
#pragma unroll
    for (int r = 0; r < 4; ++r) {
        float v = (l15 < 8) ? (acc[r] + rbv) : -3.0e38f;
        float mx = v;
#pragma unroll
        for (int m = 1; m < 16; m <<= 1) mx = fmaxf(mx, __shfl_xor(mx, m));
        float ex = (l15 < 8) ? expf(v - mx) : 0.0f;
        float s = ex;
#pragma unroll
        for (int m = 1; m < 16; m <<= 1) s += __shfl_xor(s, m);
        float p = ex / s;
        pr[r] = p;
        // top-1 (stable: tie -> lower index)
        float tv = p; int ti = l15;
#pragma unroll
        for (int m = 1; m < 16; m <<= 1) {
            float ov = __shfl_xor(tv, m); int oi = __shfl_xor(ti, m);
            if (ov > tv || (ov == tv && oi < ti)) { tv = ov; ti = oi; }
        }
        int i1 = ti; float p1 = tv;
        float tv2 = (l15 == i1) ? -1.0f : p; int ti2 = l15;
#pragma unroll
        for (int m = 1; m < 16; m <<= 1) {
            float ov = __shfl_xor(tv2, m); int oi = __shfl_xor(ti2, m);
            if (ov > tv2 || (ov == tv2 && oi < ti2)) { tv2 = ov; ti2 = oi; }
        }
        int i2 = ti2; float p2 = tv2;
        float den = p1 + p2 + 1e-6f;
        i1r[r] = i1; i2r[r] = i2; w1r[r] = p1 / den; w2r[r] = p2 / den;
    }

    // aux partials: reduce over quads (same l15 = e)
    float ps = pr[0] + pr[1] + pr[2] + pr[3];
    ps += __shfl_xor(ps, 16); ps += __shfl_xor(ps, 32);
    float mc = 0.0f;
#pragma unroll
    for (int r = 0; r < 4; ++r) mc += (i1r[r] == l15 ? 1.0f : 0.0f) + (i2r[r] == l15 ? 1.0f : 0.0f);
    mc += __shfl_xor(mc, 16); mc += __shfl_xor(mc, 32);
    if (lane < 8) {
        atomicAdd(&sum_probs[l * 64 + img * 8 + lane], ps);
        atomicAdd(&mask_cnt[l * 64 + img * 8 + lane], mc);
    }
    // binning: lane l15==0 of each quad handles its 4 tokens
    if (l15 == 0) {
#pragma unroll
        for (int r = 0; r < 4; ++r) {
            int token = tok0w + quad * 4 + r;
            int p = i1r[r] * 8 + i2r[r];
            int pos = atomicAdd(&counts[l * 64 + p], 1);
            int sidx = p * BINCAP + pos;
            btok[sidx] = token;
            bw1[sidx] = w1r[r];
            bw2[sidx] = w2r[r];
        }
    }
}

// ---------- work queue: one item per (pair, 16-token tile)
__global__ __launch_bounds__(64) void wq_kernel(
    const int* __restrict__ counts, int* __restrict__ wq, int* __restrict__ nworkp, int l)
{
    const int p = threadIdx.x;
    int cnt = counts[l * 64 + p];
    int nb = (cnt + 15) >> 4;
    int t = nb;
    for (int off = 1; off < 64; off <<= 1) {
        int y = __shfl_up(t, off);
        if (p >= off) t += y;
    }
    int start = t - nb;
    for (int i = 0; i < nb; ++i) wq[start + i] = p | ((i * 16) << 6);
    if (p == 63) nworkp[0] = t;
}

// ---------- wave-autonomous pair-expert MLP: 16 tokens/wave, zero barriers.
__global__ __launch_bounds__(256) void expert_pair(
    const short* __restrict__ Hin, short* __restrict__ Hout,
    const int* __restrict__ counts, const int* __restrict__ btok,
    const float* __restrict__ bw1, const float* __restrict__ bw2,
    const short* __restrict__ ew1t, const float* __restrict__ eb1,
    const short* __restrict__ ew2t, const float* __restrict__ eb2,
    const int* __restrict__ wq, const int* __restrict__ nworkp, int l)
{
    __shared__ __align__(16) short h1sh[4][2][16 * 72];   // per-wave, per-expert h1 [tok][bn]
    const int tid = threadIdx.x;
    const int w = tid >> 6, lane = tid & 63;
    const int quad = lane >> 4, l15 = lane & 15;
    const int nwork = nworkp[0];
    short* ha_sh = &h1sh[w][0][0];
    short* hb_sh = &h1sh[w][1][0];

    for (int wi = blockIdx.x * 4 + w; wi < nwork; wi += gridDim.x * 4) {
        const int item = wq[wi];
        const int p = item & 63;
        const int base = item >> 6;
        const int ea = p >> 3, eb = p & 7;
        const int lea = l * 8 + ea, leb = l * 8 + eb;
        const int cnt = counts[l * 64 + p];

        const int sidx = p * BINCAP + base + l15;
        const bool vmeta = (base + l15) < cnt;
        const int mytok = vmeta ? btok[sidx] : 0;
        const float myw1 = vmeta ? bw1[sidx] : 0.0f;
        const float myw2 = vmeta ? bw2[sidx] : 0.0f;

        // ---- phase 1: h1[16 tok][64 bn] = relu(H @ W1 + b1), both experts
        const short* arow = Hin + (long)mytok * DM + quad * 8;
        const short* w1a = ew1t + ((long)lea * 64 + l15) * DM + quad * 8;
        const short* w1b = ew1t + ((long)leb * 64 + l15) * DM + quad * 8;

        floatx4 acc1a[4], acc1b[4];
#pragma unroll
        for (int i = 0; i < 4; ++i) { acc1a[i] = 0.0f; acc1b[i] = 0.0f; }

        for (int k0 = 0; k0 < DM; k0 += 32) {
            bf16x8 a = *(const bf16x8*)(arow + k0);
#pragma unroll
            for (int bt = 0; bt < 4; ++bt) {
                bf16x8 ba = *(const bf16x8*)(w1a + (long)bt * 16 * DM + k0);
                bf16x8 bb = *(const bf16x8*)(w1b + (long)bt * 16 * DM + k0);
                acc1a[bt] = __builtin_amdgcn_mfma_f32_16x16x32_bf16(a, ba, acc1a[bt], 0, 0, 0);
                acc1b[bt] = __builtin_amdgcn_mfma_f32_16x16x32_bf16(a, bb, acc1b[bt], 0, 0, 0);
            }
        }
        // bias + relu -> wave-private LDS (C-layout in, A-layout out; same wave)
#pragma unroll
        for (int bt = 0; bt < 4; ++bt) {
            float b1a = eb1[lea * BN + bt * 16 + l15];
            float b1b = eb1[leb * BN + bt * 16 + l15];
#pragma unroll
            for (int r = 0; r < 4; ++r) {
                ha_sh[(quad * 4 + r) * 72 + bt * 16 + l15] = f2bf(fmaxf(acc1a[bt][r] + b1a, 0.0f));
                hb_sh[(quad * 4 + r) * 72 + bt * 16 + l15] = f2bf(fmaxf(acc1b[bt][r] + b1b, 0.0f));
            }
        }
        bf16x8 ha0 = *(const bf16x8*)&ha_sh[l15 * 72 + quad * 8];
        bf16x8 ha1 = *(const bf16x8*)&ha_sh[l15 * 72 + 32 + quad * 8];
        bf16x8 hb0 = *(const bf16x8*)&hb_sh[l15 * 72 + quad * 8];
        bf16x8 hb1 = *(const bf16x8*)&hb_sh[l15 * 72 + 32 + quad * 8];

        int tokr[4]; float w1rr[4], w2rr[4]; bool vr[4];
#pragma unroll
        for (int r = 0; r < 4; ++r) {
            tokr[r] = __shfl(mytok, quad * 4 + r);
            w1rr[r] = __shfl(myw1, quad * 4 + r);
            w2rr[r] = __shfl(myw2, quad * 4 + r);
            vr[r] = (base + quad * 4 + r) < cnt;
        }

        // ---- phase 2: out[16 tok][1024] in 64 n-tiles of 16
        const short* w2a = ew2t + ((long)lea * DM + l15) * 64 + quad * 8;
        const short* w2b = ew2t + ((long)leb * DM + l15) * 64 + quad * 8;
        for (int n0 = 0; n0 < DM; n0 += 16) {
            const long wo = (long)n0 * 64;
            bf16x8 wa0 = *(const bf16x8*)(w2a + wo);
            bf16x8 wa1 = *(const bf16x8*)(w2a + wo + 32);
            bf16x8 wb0 = *(const bf16x8*)(w2b + wo);
            bf16x8 wb1 = *(const bf16x8*)(w2b + wo + 32);
            floatx4 a2 = 0.0f, b2 = 0.0f;
            a2 = __builtin_amdgcn_mfma_f32_16x16x32_bf16(ha0, wa0, a2, 0, 0, 0);
            a2 = __builtin_amdgcn_mfma_f32_16x16x32_bf16(ha1, wa1, a2, 0, 0, 0);
            b2 = __builtin_amdgcn_mfma_f32_16x16x32_bf16(hb0, wb0, b2, 0, 0, 0);
            b2 = __builtin_amdgcn_mfma_f32_16x16x32_bf16(hb1, wb1, b2, 0, 0, 0);
            float bba = eb2[lea * DM + n0 + l15];
            float bbb = eb2[leb * DM + n0 + l15];
#pragma unroll
            for (int r = 0; r < 4; ++r) {
                if (vr[r]) {
                    long idx = (long)tokr[r] * DM + n0 + l15;
                    float res = bf2f(Hin[idx]);
                    Hout[idx] = f2bf(res + w1rr[r] * (a2[r] + bba) + w2rr[r] * (b2[r] + bbb));
                }
            }
        }
    }
}

// ---------- vision_proj
__global__ __launch_bounds__(256) void vproj_kernel(
    const float* __restrict__ pooled, const float* __restrict__ w_out,
    const float* __restrict__ b_out, float* __restrict__ outp)
{
    __shared__ float ps[8 * 128];
    const int tid = threadIdx.x;
    const int n = blockIdx.x * 256 + tid;
    const int d0 = blockIdx.y * 128;
#pragma unroll
    for (int i = 0; i < 4; ++i) {
        int idx = tid + i * 256;
        ps[idx] = pooled[(idx >> 7) * DM + d0 + (idx & 127)];
    }
    __syncthreads();
    float acc[8];
    float binit = (blockIdx.y == 0) ? b_out[n] : 0.0f;
#pragma unroll
    for (int img = 0; img < 8; ++img) acc[img] = binit;
    for (int d = 0; d < 128; ++d) {
        float wv = w_out[(long)(d0 + d) * DOUT + n];
#pragma unroll
        for (int img = 0; img < 8; ++img) acc[img] += ps[img * 128 + d] * wv;
    }
#pragma unroll
    for (int img = 0; img < 8; ++img) atomicAdd(&outp[img * DOUT + n], acc[img]);
}

// ---------- aux
__global__ __launch_bounds__(64) void aux_kernel(
    const float* __restrict__ sum_probs, const float* __restrict__ mask_cnt,
    float* __restrict__ outp)
{
    const int tid = threadIdx.x;
    float v = 0.0f;
    if (tid < 32) {
        float s = 0.0f;
#pragma unroll
        for (int e = 0; e < 8; ++e) s += sum_probs[tid * 8 + e] * mask_cnt[tid * 8 + e];
        v = s * (8.0f / (4096.0f * 4096.0f));
    }
    for (int off = 32; off > 0; off >>= 1) v += __shfl_down(v, off);
    if (tid == 0) outp[0] = v;
}

extern "C" void kernel_launch(void* const* d_in, const int* in_sizes, int n_in,
                              void* d_out, int out_size, void* d_ws, size_t ws_size,
                              hipStream_t stream) {
    const float* X       = (const float*)d_in[0];
    const float* w_in    = (const float*)d_in[2];
    const float* w_sc1   = (const float*)d_in[3];
    const float* b_sc1   = (const float*)d_in[4];
    const float* w_sc2   = (const float*)d_in[5];
    const float* b_sc2   = (const float*)d_in[6];
    const float* w_rimg  = (const float*)d_in[7];
    const float* w_rskin = (const float*)d_in[8];
    const float* ew1     = (const float*)d_in[9];
    const float* eb1     = (const float*)d_in[10];
    const float* ew2     = (const float*)d_in[11];
    const float* eb2     = (const float*)d_in[12];
    const float* w_out   = (const float*)d_in[13];
    const float* b_out   = (const float*)d_in[14];

    float* out = (float*)d_out;
    char* ws = (char*)d_ws;

    short* H0   = (short*)(ws + OFF_H0);
    short* H1   = (short*)(ws + OFF_H1);
    short* Xb   = (short*)(ws + OFF_XB);
    short* Wbt  = (short*)(ws + OFF_WBT);
    short* ew1t = (short*)(ws + OFF_E1T);
    short* ew2t = (short*)(ws + OFF_E2T);
    int*   btok = (int*)(ws + OFF_BTOK);
    float* bw1  = (float*)(ws + OFF_BW1);
    float* bw2  = (float*)(ws + OFF_BW2);
    int*   wq   = (int*)(ws + OFF_WQ);
    int*   counts    = (int*)(ws + OFF_Z);
    int*   nworkp    = (int*)(ws + OFF_Z + 1024);
    float* sum_probs = (float*)(ws + OFF_Z + 1088);
    float* mask_cnt  = (float*)(ws + OFF_Z + 2112);
    float* g         = (float*)(ws + OFF_Z + 3136);
    float* hsg       = (float*)(ws + OFF_Z + 35904);
    float* rb        = (float*)(ws + OFF_RB);
    short* wrT       = (short*)(ws + OFF_WRT);

    hipMemsetAsync(d_out, 0, (size_t)out_size * sizeof(float), stream);
    hipMemsetAsync(ws + OFF_Z, 0, Z_BYTES, stream);

    dim3 b256(256);
    convx_kernel<<<TT, b256, 0, stream>>>(X, Xb);
    transp_kernel<<<dim3(19, 16, 1), b256, 0, stream>>>(w_in, Wbt, DIN, DM, KP);
    transp_kernel<<<dim3(16, 1, 32), b256, 0, stream>>>(ew1, ew1t, DM, BN, DM);
    transp_kernel<<<dim3(1, 16, 32), b256, 0, stream>>>(ew2, ew2t, BN, DM, BN);
    wrt_kernel<<<64, b256, 0, stream>>>(w_rimg, wrT);
    gemm_in_mfma<<<dim3(256, 8), b256, 0, stream>>>(Xb, Wbt, H0);
    colmean_kernel<<<dim3(4, 8, 16), b256, 0, stream>>>(H0, g);
    skin1_kernel<<<8, b256, 0, stream>>>(g, w_sc1, b_sc1, hsg);
    skin2_kernel<<<1, b256, 0, stream>>>(hsg, w_sc2, b_sc2, w_rskin, out + 40961, rb);

    short* Hc = H0;
    short* Hn = H1;
    for (int l = 0; l < NL; ++l) {
        router_kernel<<<512, b256, 0, stream>>>(Hc, wrT, rb, counts, btok, bw1, bw2,
                                                sum_probs, mask_cnt, l);
        wq_kernel<<<1, 64, 0, stream>>>(counts, wq, nworkp, l);
        expert_pair<<<640, b256, 0, stream>>>(Hc, Hn, counts, btok, bw1, bw2,
                                              ew1t, eb1, ew2t, eb2, wq, nworkp, l);
        short* tmp = Hc; Hc = Hn; Hn = tmp;
    }
    colmean_kernel<<<dim3(4, 8, 16), b256, 0, stream>>>(Hc, out);
    vproj_kernel<<<dim3(16, 8), b256, 0, stream>>>(out, w_out, b_out, out + 8192);
    aux_kernel<<<1, 64, 0, stream>>>(sum_probs, mask_cnt, out + 40960);
}